// Round 9
// baseline (304.978 us; speedup 1.0000x reference)
//
#include <hip/hip_runtime.h>

#define N_RES     300000
#define N_RESTYPE 21
#define BLK       64

// unaligned-tolerant vector loads (global_load_dwordx4/x2 need only 4B align)
typedef float f4u __attribute__((ext_vector_type(4), aligned(4)));
typedef float f2u __attribute__((ext_vector_type(2), aligned(4)));

__device__ __forceinline__ void ld12g(const float* p, float* X) {
    // p 16B-aligned; 3x global_load_dwordx4 (L1-cached table gather)
    const float4* q = reinterpret_cast<const float4*>(p);
    float4 a = q[0], b = q[1], c = q[2];
    X[0]=a.x; X[1]=a.y; X[2]=a.z;  X[3]=a.w;
    X[4]=b.x; X[5]=b.y; X[6]=b.z;  X[7]=b.w;
    X[8]=c.x; X[9]=c.y; X[10]=c.z; X[11]=c.w;
}

// D = combine(X, Y): R_D = R_X @ R_Y ; t_D = R_X @ t_Y + t_X
// layout: [0..8] row-major 3x3 R, [9..11] t. D may alias Y (locals first).
__device__ __forceinline__ void combine_full(const float* X, const float* Y, float* D) {
    float R[9], t[3];
    #pragma unroll
    for (int r = 0; r < 3; ++r) {
        #pragma unroll
        for (int c = 0; c < 3; ++c) {
            R[r*3+c] = X[r*3+0]*Y[0+c] + X[r*3+1]*Y[3+c] + X[r*3+2]*Y[6+c];
        }
        t[r] = X[r*3+0]*Y[9] + X[r*3+1]*Y[10] + X[r*3+2]*Y[11] + X[9+r];
    }
    #pragma unroll
    for (int k = 0; k < 9; ++k) D[k] = R[k];
    D[9]=t[0]; D[10]=t[1]; D[11]=t[2];
}

// 64-thread blocks, no LDS: occupancy bounded only by VGPR (cap 128 via min
// 4 waves/EU). 4688 blocks keep all 256 CUs fed; tables (17KB) live in L1/L2.
__global__ __launch_bounds__(BLK, 4) void backbone_kernel(
    const float* __restrict__ bb,     // (N,7)
    const float* __restrict__ sc,     // (N,7,2)
    const float* __restrict__ pos0,   // (N,3)
    const float* __restrict__ tfm,    // (21,8,4,3)
    const float* __restrict__ rig,    // (21,24,3)
    const int*   __restrict__ rtype,  // (N)
    const int*   __restrict__ tdep,   // (21,8)
    const int*   __restrict__ rdep,   // (21,24)
    float*       __restrict__ out)    // R (N,24,3) then opr0 (N,4,3)
{
    const int n = blockIdx.x * BLK + threadIdx.x;
    if (n >= N_RES) return;

    const int rt = rtype[n];
    const float* tbase = tfm + rt * 96;   // rt*384B: 16B-aligned rows
    const float* rbase = rig + rt * 72;   // rt*288B: 16B-aligned groups

    // ---- per-residue inputs (vectorized; overlap trick avoids OOB) ----
    const float* bbn = bb + (size_t)n * 7;
    f4u bv0 = *reinterpret_cast<const f4u*>(bbn);       // w x y z
    f4u bv1 = *reinterpret_cast<const f4u*>(bbn + 3);   // z t4 t5 t6
    float w = bv0.x, x = bv0.y, y = bv0.z, z = bv0.w;

    const float* pn = pos0 + (size_t)n * 3;
    f2u pv = *reinterpret_cast<const f2u*>(pn);
    float t0x = 0.1f * bv1.y + pv.x;
    float t0y = 0.1f * bv1.z + pv.y;
    float t0z = 0.1f * bv1.w + pn[2];

    const float* scn = sc + (size_t)n * 14;
    f4u s0 = *reinterpret_cast<const f4u*>(scn);        // c0 s0 c1 s1
    f4u s1 = *reinterpret_cast<const f4u*>(scn + 4);    // c2 s2 c3 s3
    f4u s2 = *reinterpret_cast<const f4u*>(scn + 8);    // c4 s4 c5 s5
    f2u s3 = *reinterpret_cast<const f2u*>(scn + 12);   // c6 s6
    float csc[7] = {s0.x, s0.z, s1.x, s1.z, s2.x, s2.z, s3.x};
    float css[7] = {s0.y, s0.w, s1.y, s1.w, s2.y, s2.w, s3.y};

    // ---- quaternion (unnormalized, as in reference) -> Y0 ----
    float ww = w*w, xx = x*x, yy = y*y, zz = z*z;
    float xy = x*y, wz = w*z, xz = x*z, wy = w*y, yz = y*z, wx = w*x;
    float Y0[12];
    Y0[0] = ww + xx - yy - zz;
    Y0[1] = 2.0f * (xy - wz);
    Y0[2] = 2.0f * (xz + wy);
    Y0[3] = 2.0f * (xy + wz);
    Y0[4] = ww - xx + yy - zz;
    Y0[5] = 2.0f * (yz - wx);
    Y0[6] = 2.0f * (xz - wy);
    Y0[7] = 2.0f * (yz + wx);
    Y0[8] = ww - xx - yy + zz;
    Y0[9] = t0x; Y0[10] = t0y; Y0[11] = t0z;

    // ---- opr[i] = combine(transforms[rt][i], local[i]) ----
    float opr[8][12];
    {
        float X[12];
        ld12g(tbase, X);
        combine_full(X, Y0, opr[0]);
    }
    #pragma unroll
    for (int i = 1; i < 8; ++i) {
        float X[12];
        ld12g(tbase + i * 12, X);
        float cj = csc[i-1], sj = css[i-1];
        // local rot about x: X @ [[1,0,0],[0,c,-s],[0,s,c]], t unchanged
        #pragma unroll
        for (int r = 0; r < 3; ++r) {
            opr[i][r*3+0] = X[r*3+0];
            opr[i][r*3+1] = X[r*3+1]*cj + X[r*3+2]*sj;
            opr[i][r*3+2] = X[r*3+2]*cj - X[r*3+1]*sj;
        }
        opr[i][9]  = X[9];
        opr[i][10] = X[10];
        opr[i][11] = X[11];
    }

    // ---- sequential dependency chain (tdep[i] < i), cndmask select ----
    const int* tdn = tdep + rt * 8;
    #pragma unroll
    for (int i = 1; i < 8; ++i) {
        int dep = tdn[i];
        float P[12];
        #pragma unroll
        for (int k = 0; k < 12; ++k) P[k] = opr[0][k];
        #pragma unroll
        for (int j = 1; j < 8; ++j) {
            if (j < i) {             // compile-time prune after unroll
                bool m = (dep == j);
                #pragma unroll
                for (int k = 0; k < 12; ++k) P[k] = m ? opr[j][k] : P[k];
            }
        }
        combine_full(P, opr[i], opr[i]);
    }

    // ---- 24 atoms: G = opr[rdep[a]] via 3-level cndmask tree ----
    const int* rdn = rdep + rt * 24;
    float* outR = out + (size_t)n * 72;
    #pragma unroll
    for (int g4 = 0; g4 < 6; ++g4) {
        float V[12];
        ld12g(rbase + g4 * 12, V);       // 4 atoms' vectors
        float ob[12];
        #pragma unroll
        for (int aa = 0; aa < 4; ++aa) {
            int a = g4 * 4 + aa;
            int r = rdn[a];
            bool b0 = (r & 1), b1 = (r & 2), b2 = (r & 4);
            float g[12];
            #pragma unroll
            for (int k = 0; k < 12; ++k) {
                float s01 = b0 ? opr[1][k] : opr[0][k];
                float s23 = b0 ? opr[3][k] : opr[2][k];
                float s45 = b0 ? opr[5][k] : opr[4][k];
                float s67 = b0 ? opr[7][k] : opr[6][k];
                float s0123 = b1 ? s23 : s01;
                float s4567 = b1 ? s67 : s45;
                g[k] = b2 ? s4567 : s0123;
            }
            float vx = V[aa*3+0], vy = V[aa*3+1], vz = V[aa*3+2];
            ob[aa*3+0] = g[0]*vx + g[1]*vy + g[2]*vz + g[9];
            ob[aa*3+1] = g[3]*vx + g[4]*vy + g[5]*vz + g[10];
            ob[aa*3+2] = g[6]*vx + g[7]*vy + g[8]*vz + g[11];
        }
        float4* op = reinterpret_cast<float4*>(outR + g4 * 12);
        op[0] = make_float4(ob[0], ob[1], ob[2],  ob[3]);
        op[1] = make_float4(ob[4], ob[5], ob[6],  ob[7]);
        op[2] = make_float4(ob[8], ob[9], ob[10], ob[11]);
    }

    // ---- out2: final opr[:,0] (never modified by the chain) ----
    float4* o2 = reinterpret_cast<float4*>(out + (size_t)N_RES * 72 + (size_t)n * 12);
    o2[0] = make_float4(opr[0][0], opr[0][1], opr[0][2],  opr[0][3]);
    o2[1] = make_float4(opr[0][4], opr[0][5], opr[0][6],  opr[0][7]);
    o2[2] = make_float4(opr[0][8], opr[0][9], opr[0][10], opr[0][11]);
}

extern "C" void kernel_launch(void* const* d_in, const int* in_sizes, int n_in,
                              void* d_out, int out_size, void* d_ws, size_t ws_size,
                              hipStream_t stream) {
    const float* bb    = (const float*)d_in[0];
    const float* sc    = (const float*)d_in[1];
    const float* pos0  = (const float*)d_in[2];
    const float* tfm   = (const float*)d_in[3];
    const float* rig   = (const float*)d_in[4];
    const int*   rtype = (const int*)d_in[5];
    const int*   tdep  = (const int*)d_in[6];
    const int*   rdep  = (const int*)d_in[7];
    float* out = (float*)d_out;

    const int blocks = (N_RES + BLK - 1) / BLK;
    backbone_kernel<<<blocks, BLK, 0, stream>>>(bb, sc, pos0, tfm, rig,
                                                rtype, tdep, rdep, out);
}

// Round 10
// 163.901 us; speedup vs baseline: 1.8607x; 1.8607x over previous
//
#include <hip/hip_runtime.h>

#define N_RES     300000
#define N_RESTYPE 21
#define BLK       256

// padded LDS strides (in elements) to spread restype gathers across banks
#define TFM_STRIDE  100   // 96 floats used per restype (8 rigids x 12); 400B: 16B-multiple
#define RIG_STRIDE  76    // 72 floats used per restype (24 atoms x 3);  304B: 16B-multiple
#define TDEP_STRIDE 9     // 8 ints used
#define RDEP_STRIDE 25    // 24 ints used

// unaligned-tolerant vector loads (global_load_dwordx4/x2 need only 4B align)
typedef float f4u __attribute__((ext_vector_type(4), aligned(4)));
typedef float f2u __attribute__((ext_vector_type(2), aligned(4)));

__device__ __forceinline__ void ld12(const float* p, float* X) {
    // p 16B-aligned; 3x ds_read_b128
    const float4* q = reinterpret_cast<const float4*>(p);
    float4 a = q[0], b = q[1], c = q[2];
    X[0]=a.x; X[1]=a.y; X[2]=a.z;  X[3]=a.w;
    X[4]=b.x; X[5]=b.y; X[6]=b.z;  X[7]=b.w;
    X[8]=c.x; X[9]=c.y; X[10]=c.z; X[11]=c.w;
}

// D = combine(X, Y): R_D = R_X @ R_Y ; t_D = R_X @ t_Y + t_X
// layout: [0..8] row-major 3x3 R, [9..11] t. D may alias Y (locals first).
__device__ __forceinline__ void combine_full(const float* X, const float* Y, float* D) {
    float R[9], t[3];
    #pragma unroll
    for (int r = 0; r < 3; ++r) {
        #pragma unroll
        for (int c = 0; c < 3; ++c) {
            R[r*3+c] = X[r*3+0]*Y[0+c] + X[r*3+1]*Y[3+c] + X[r*3+2]*Y[6+c];
        }
        t[r] = X[r*3+0]*Y[9] + X[r*3+1]*Y[10] + X[r*3+2]*Y[11] + X[9+r];
    }
    #pragma unroll
    for (int k = 0; k < 9; ++k) D[k] = R[k];
    D[9]=t[0]; D[10]=t[1]; D[11]=t[2];
}

// min 3 waves/EU -> unified VGPR+AGPR budget ~170/wave. Live set ~140 floats
// (opr 96 + group working set ~30 + addressing) -> fits without scratch.
// (R9 proved budget 128 spills to scratch: 407MB WRITE. R7 at min-2 sat at
//  ~230 regs / 2 waves per SIMD. This targets 3 waves/SIMD.)
__global__ __launch_bounds__(BLK, 3) void backbone_kernel(
    const float* __restrict__ bb,     // (N,7)
    const float* __restrict__ sc,     // (N,7,2)
    const float* __restrict__ pos0,   // (N,3)
    const float* __restrict__ tfm,    // (21,8,4,3)
    const float* __restrict__ rig,    // (21,24,3)
    const int*   __restrict__ rtype,  // (N)
    const int*   __restrict__ tdep,   // (21,8)
    const int*   __restrict__ rdep,   // (21,24)
    float*       __restrict__ out)    // R (N,24,3) then opr0 (N,4,3)
{
    __shared__ __align__(16) float lds_tfm [N_RESTYPE * TFM_STRIDE];
    __shared__ __align__(16) float lds_rig [N_RESTYPE * RIG_STRIDE];
    __shared__ int   lds_tdep[N_RESTYPE * TDEP_STRIDE];
    __shared__ int   lds_rdep[N_RESTYPE * RDEP_STRIDE];

    const int tid = threadIdx.x;
    for (int idx = tid; idx < N_RESTYPE * 96; idx += BLK) {
        int r = idx / 96; int c = idx - r * 96;
        lds_tfm[r * TFM_STRIDE + c] = tfm[idx];
    }
    for (int idx = tid; idx < N_RESTYPE * 72; idx += BLK) {
        int r = idx / 72; int c = idx - r * 72;
        lds_rig[r * RIG_STRIDE + c] = rig[idx];
    }
    for (int idx = tid; idx < N_RESTYPE * 8; idx += BLK) {
        int r = idx >> 3; int c = idx & 7;
        lds_tdep[r * TDEP_STRIDE + c] = tdep[idx];
    }
    for (int idx = tid; idx < N_RESTYPE * 24; idx += BLK) {
        int r = idx / 24; int c = idx - r * 24;
        lds_rdep[r * RDEP_STRIDE + c] = rdep[idx];
    }
    __syncthreads();

    const int n = blockIdx.x * BLK + tid;
    if (n >= N_RES) return;

    const int rt = rtype[n];

    // ---- per-residue inputs (vectorized; overlap trick avoids OOB) ----
    const float* bbn = bb + (size_t)n * 7;
    f4u bv0 = *reinterpret_cast<const f4u*>(bbn);       // w x y z
    f4u bv1 = *reinterpret_cast<const f4u*>(bbn + 3);   // z t4 t5 t6
    float w = bv0.x, x = bv0.y, y = bv0.z, z = bv0.w;

    const float* pn = pos0 + (size_t)n * 3;
    f2u pv = *reinterpret_cast<const f2u*>(pn);
    float t0x = 0.1f * bv1.y + pv.x;
    float t0y = 0.1f * bv1.z + pv.y;
    float t0z = 0.1f * bv1.w + pn[2];

    const float* scn = sc + (size_t)n * 14;
    f4u s0 = *reinterpret_cast<const f4u*>(scn);        // c0 s0 c1 s1
    f4u s1 = *reinterpret_cast<const f4u*>(scn + 4);    // c2 s2 c3 s3
    f4u s2 = *reinterpret_cast<const f4u*>(scn + 8);    // c4 s4 c5 s5
    f2u s3 = *reinterpret_cast<const f2u*>(scn + 12);   // c6 s6
    float csc[7] = {s0.x, s0.z, s1.x, s1.z, s2.x, s2.z, s3.x};
    float css[7] = {s0.y, s0.w, s1.y, s1.w, s2.y, s2.w, s3.y};

    // ---- quaternion (unnormalized, as in reference) -> Y0 ----
    float ww = w*w, xx = x*x, yy = y*y, zz = z*z;
    float xy = x*y, wz = w*z, xz = x*z, wy = w*y, yz = y*z, wx = w*x;
    float Y0[12];
    Y0[0] = ww + xx - yy - zz;
    Y0[1] = 2.0f * (xy - wz);
    Y0[2] = 2.0f * (xz + wy);
    Y0[3] = 2.0f * (xy + wz);
    Y0[4] = ww - xx + yy - zz;
    Y0[5] = 2.0f * (yz - wx);
    Y0[6] = 2.0f * (xz - wy);
    Y0[7] = 2.0f * (yz + wx);
    Y0[8] = ww - xx - yy + zz;
    Y0[9] = t0x; Y0[10] = t0y; Y0[11] = t0z;

    // ---- opr[i] = combine(transforms[rt][i], local[i]) ----
    float opr[8][12];
    {
        float X[12];
        ld12(&lds_tfm[rt * TFM_STRIDE], X);
        combine_full(X, Y0, opr[0]);
    }
    #pragma unroll
    for (int i = 1; i < 8; ++i) {
        float X[12];
        ld12(&lds_tfm[rt * TFM_STRIDE + i * 12], X);
        float cj = csc[i-1], sj = css[i-1];
        // local rot about x: X @ [[1,0,0],[0,c,-s],[0,s,c]], t unchanged
        #pragma unroll
        for (int r = 0; r < 3; ++r) {
            opr[i][r*3+0] = X[r*3+0];
            opr[i][r*3+1] = X[r*3+1]*cj + X[r*3+2]*sj;
            opr[i][r*3+2] = X[r*3+2]*cj - X[r*3+1]*sj;
        }
        opr[i][9]  = X[9];
        opr[i][10] = X[10];
        opr[i][11] = X[11];
    }

    // ---- sequential dependency chain (tdep[i] < i), cndmask select ----
    #pragma unroll
    for (int i = 1; i < 8; ++i) {
        int dep = lds_tdep[rt * TDEP_STRIDE + i];
        float P[12];
        #pragma unroll
        for (int k = 0; k < 12; ++k) P[k] = opr[0][k];
        #pragma unroll
        for (int j = 1; j < 8; ++j) {
            if (j < i) {             // compile-time prune after unroll
                bool m = (dep == j);
                #pragma unroll
                for (int k = 0; k < 12; ++k) P[k] = m ? opr[j][k] : P[k];
            }
        }
        combine_full(P, opr[i], opr[i]);
    }

    // ---- out2: final opr[:,0] (never modified by the chain) ----
    float4* o2 = reinterpret_cast<float4*>(out + (size_t)N_RES * 72 + (size_t)n * 12);
    o2[0] = make_float4(opr[0][0], opr[0][1], opr[0][2],  opr[0][3]);
    o2[1] = make_float4(opr[0][4], opr[0][5], opr[0][6],  opr[0][7]);
    o2[2] = make_float4(opr[0][8], opr[0][9], opr[0][10], opr[0][11]);

    // ---- 24 atoms, k-major gather: read each opr[j][k] once per 4-atom
    //      group, select for all 4 atoms (4x fewer opr reads than per-atom) ----
    const float* rbase = &lds_rig[rt * RIG_STRIDE];
    float* outR = out + (size_t)n * 72;
    #pragma unroll
    for (int g4 = 0; g4 < 6; ++g4) {
        float V[12];
        ld12(rbase + g4 * 12, V);       // 4 atoms' vectors
        int  rv[4];
        #pragma unroll
        for (int aa = 0; aa < 4; ++aa) rv[aa] = lds_rdep[rt * RDEP_STRIDE + g4*4 + aa];

        float ob[12];
        #pragma unroll
        for (int k = 0; k < 12; ++k) {
            float o0 = opr[0][k], o1 = opr[1][k], o2v = opr[2][k], o3 = opr[3][k];
            float o4 = opr[4][k], o5 = opr[5][k], o6  = opr[6][k], o7 = opr[7][k];
            #pragma unroll
            for (int aa = 0; aa < 4; ++aa) {
                int r = rv[aa];
                bool b0 = (r & 1), b1 = (r & 2), b2 = (r & 4);
                float s01 = b0 ? o1 : o0;
                float s23 = b0 ? o3 : o2v;
                float s45 = b0 ? o5 : o4;
                float s67 = b0 ? o7 : o6;
                float s0123 = b1 ? s23 : s01;
                float s4567 = b1 ? s67 : s45;
                float ga = b2 ? s4567 : s0123;
                if (k < 9) {
                    const int row = k / 3, col = k % 3;
                    if (col == 0) ob[aa*3+row]  = ga * V[aa*3+0];
                    else          ob[aa*3+row] += ga * V[aa*3+col];
                } else {
                    ob[aa*3+(k-9)] += ga;   // + t, same summation order as ref
                }
            }
        }
        float4* op = reinterpret_cast<float4*>(outR + g4 * 12);
        op[0] = make_float4(ob[0], ob[1], ob[2],  ob[3]);
        op[1] = make_float4(ob[4], ob[5], ob[6],  ob[7]);
        op[2] = make_float4(ob[8], ob[9], ob[10], ob[11]);
    }
}

extern "C" void kernel_launch(void* const* d_in, const int* in_sizes, int n_in,
                              void* d_out, int out_size, void* d_ws, size_t ws_size,
                              hipStream_t stream) {
    const float* bb    = (const float*)d_in[0];
    const float* sc    = (const float*)d_in[1];
    const float* pos0  = (const float*)d_in[2];
    const float* tfm   = (const float*)d_in[3];
    const float* rig   = (const float*)d_in[4];
    const int*   rtype = (const int*)d_in[5];
    const int*   tdep  = (const int*)d_in[6];
    const int*   rdep  = (const int*)d_in[7];
    float* out = (float*)d_out;

    const int blocks = (N_RES + BLK - 1) / BLK;
    backbone_kernel<<<blocks, BLK, 0, stream>>>(bb, sc, pos0, tfm, rig,
                                                rtype, tdep, rdep, out);
}